// Round 7
// baseline (73.107 us; speedup 1.0000x reference)
//
#include <hip/hip_runtime.h>

#define LOG2E 1.4426950408889634f
#define TWO_LOG2E 2.885390081777927f

__device__ __forceinline__ float fast_exp2(float x) { return __builtin_amdgcn_exp2f(x); }
__device__ __forceinline__ float fast_rcp(float x)  { return __builtin_amdgcn_rcpf(x); }

// ---------------------------------------------------------------------------
// K1: projections + exp transform. Virtual M=4096 rows: blocks 0..255 ->
// exp2(2*log2e * query*Wq) -> eq, blocks 256..511 -> value*Wv -> ek.
// 8 rows per block, 256 threads (one output column each).
// ---------------------------------------------------------------------------
__global__ __launch_bounds__(256) void proj_kernel(
    const float* __restrict__ query, const float* __restrict__ value,
    const float* __restrict__ Wq, const float* __restrict__ Wv,
    float* __restrict__ eq, float* __restrict__ ek)
{
    __shared__ float in_lds[8 * 256];
    const int t = threadIdx.x;
    const int row0 = blockIdx.x * 8;
    const float* src; const float* W; float* dst;
    if (row0 < 2048) { src = query + (size_t)row0 * 256; W = Wq; dst = eq + (size_t)row0 * 256; }
    else { const int r = row0 - 2048; src = value + (size_t)r * 256; W = Wv; dst = ek + (size_t)r * 256; }

    const float4* s4 = (const float4*)src;
    float4* l4 = (float4*)in_lds;
    l4[t] = s4[t];
    l4[t + 256] = s4[t + 256];
    __syncthreads();

    float acc[8];
#pragma unroll
    for (int r = 0; r < 8; ++r) acc[r] = 0.f;

    for (int d = 0; d < 256; d += 4) {
        const float w0 = W[(d + 0) * 256 + t];
        const float w1 = W[(d + 1) * 256 + t];
        const float w2 = W[(d + 2) * 256 + t];
        const float w3 = W[(d + 3) * 256 + t];
#pragma unroll
        for (int r = 0; r < 8; ++r) {
            const float4 v = *(const float4*)&in_lds[r * 256 + d];
            acc[r] = fmaf(v.x, w0, acc[r]);
            acc[r] = fmaf(v.y, w1, acc[r]);
            acc[r] = fmaf(v.z, w2, acc[r]);
            acc[r] = fmaf(v.w, w3, acc[r]);
        }
    }
#pragma unroll
    for (int r = 0; r < 8; ++r) dst[r * 256 + t] = fast_exp2(acc[r] * TWO_LOG2E);
}

// ---------------------------------------------------------------------------
// K2: shifted additive scores, d-split x2, PAIRED-RCP body.
//   score*[q,k] = sum_d (-2*scale[d]) / (eq*ek + 1)   (global shift, softmax
//   cancels). Pairs (d,d+1): s1/A + s2/B = (s1*B + s2*A) / (A*B) -> ONE rcp
//   per two d-terms: 6 full-rate + 1 trans = 10 cyc/wave-elem.
// Each block: 32q x 32k tile, d-range 128 (dh = blockIdx.z&1), whole chunk
// staged once (ONE barrier). Partial scores -> part0/part1 (plain stores).
// Grid (16,16,8) = 2048 blocks = 8192 waves. LDS stride 130: float2-aligned,
// k-row bank stride 4 mod 32 -> 2-way (free), q rows broadcast per ty.
// ---------------------------------------------------------------------------
#define SQ_ST 130
__global__ __launch_bounds__(256) void scores_kernel(
    const float* __restrict__ eq, const float* __restrict__ ek,
    const float* __restrict__ scale,
    float* __restrict__ part0, float* __restrict__ part1)
{
    __shared__ float q_lds[32 * SQ_ST];
    __shared__ float k_lds[32 * SQ_ST];
    __shared__ float sc_lds[128];

    const int t = threadIdx.x;
    const int tx = t & 15, ty = t >> 4;
    const int kt = blockIdx.x, qt = blockIdx.y;
    const int b = blockIdx.z >> 1, dh = blockIdx.z & 1;
    const int d0 = dh * 128;
    const float* qbase = eq + (size_t)(b * 512 + qt * 32) * 256 + d0;
    const float* kbase = ek + (size_t)(b * 512 + kt * 32) * 256 + d0;

    if (t < 128) sc_lds[t] = -2.f * scale[d0 + t];

#pragma unroll
    for (int l = 0; l < 4; ++l) {
        const int idx = t + 256 * l;
        const int row = idx >> 5, c4 = (idx & 31) * 4;
        const float4 qv = *(const float4*)&qbase[row * 256 + c4];
        const float4 kv = *(const float4*)&kbase[row * 256 + c4];
        *(float2*)&q_lds[row * SQ_ST + c4]     = make_float2(qv.x, qv.y);
        *(float2*)&q_lds[row * SQ_ST + c4 + 2] = make_float2(qv.z, qv.w);
        *(float2*)&k_lds[row * SQ_ST + c4]     = make_float2(kv.x, kv.y);
        *(float2*)&k_lds[row * SQ_ST + c4 + 2] = make_float2(kv.z, kv.w);
    }
    __syncthreads();

    float a00 = 0.f, a01 = 0.f, a10 = 0.f, a11 = 0.f;

#pragma unroll 4
    for (int d = 0; d < 128; d += 2) {
        const float2 s2 = *(const float2*)&sc_lds[d];
        const float2 qa = *(const float2*)&q_lds[(ty * 2 + 0) * SQ_ST + d];
        const float2 qb = *(const float2*)&q_lds[(ty * 2 + 1) * SQ_ST + d];
        const float2 ka = *(const float2*)&k_lds[(tx * 2 + 0) * SQ_ST + d];
        const float2 kb = *(const float2*)&k_lds[(tx * 2 + 1) * SQ_ST + d];

        {   // (qa, ka) -> a00
            const float A = fmaf(qa.x, ka.x, 1.f), B = fmaf(qa.y, ka.y, 1.f);
            a00 = fmaf(fmaf(s2.y, A, s2.x * B), fast_rcp(A * B), a00);
        }
        {   // (qa, kb) -> a01
            const float A = fmaf(qa.x, kb.x, 1.f), B = fmaf(qa.y, kb.y, 1.f);
            a01 = fmaf(fmaf(s2.y, A, s2.x * B), fast_rcp(A * B), a01);
        }
        {   // (qb, ka) -> a10
            const float A = fmaf(qb.x, ka.x, 1.f), B = fmaf(qb.y, ka.y, 1.f);
            a10 = fmaf(fmaf(s2.y, A, s2.x * B), fast_rcp(A * B), a10);
        }
        {   // (qb, kb) -> a11
            const float A = fmaf(qb.x, kb.x, 1.f), B = fmaf(qb.y, kb.y, 1.f);
            a11 = fmaf(fmaf(s2.y, A, s2.x * B), fast_rcp(A * B), a11);
        }
    }

    float* part = dh ? part1 : part0;
    const int qrow = qt * 32 + ty * 2;
    const int kcol = kt * 32 + tx * 2;
    *(float2*)&part[(size_t)(b * 512 + qrow + 0) * 512 + kcol] = make_float2(a00, a01);
    *(float2*)&part[(size_t)(b * 512 + qrow + 1) * 512 + kcol] = make_float2(a10, a11);
}

// ---------------------------------------------------------------------------
// K3: sum the two d-partials, softmax over last dim (512), write attn.
// One wave per row.
// ---------------------------------------------------------------------------
__global__ __launch_bounds__(64) void softmax_kernel(
    const float* __restrict__ part0, const float* __restrict__ part1,
    float* __restrict__ attn)
{
    const int row = blockIdx.x;
    const float4* p0 = (const float4*)(part0 + (size_t)row * 512);
    const float4* p1 = (const float4*)(part1 + (size_t)row * 512);
    float4* po = (float4*)(attn + (size_t)row * 512);
    const int t = threadIdx.x;

    float4 a = p0[t], a2 = p1[t];
    a.x += a2.x; a.y += a2.y; a.z += a2.z; a.w += a2.w;
    float4 b = p0[t + 64], b2 = p1[t + 64];
    b.x += b2.x; b.y += b2.y; b.z += b2.z; b.w += b2.w;

    float m = fmaxf(fmaxf(fmaxf(a.x, a.y), fmaxf(a.z, a.w)),
                    fmaxf(fmaxf(b.x, b.y), fmaxf(b.z, b.w)));
#pragma unroll
    for (int off = 32; off; off >>= 1) m = fmaxf(m, __shfl_xor(m, off));

    a.x = fast_exp2((a.x - m) * LOG2E); a.y = fast_exp2((a.y - m) * LOG2E);
    a.z = fast_exp2((a.z - m) * LOG2E); a.w = fast_exp2((a.w - m) * LOG2E);
    b.x = fast_exp2((b.x - m) * LOG2E); b.y = fast_exp2((b.y - m) * LOG2E);
    b.z = fast_exp2((b.z - m) * LOG2E); b.w = fast_exp2((b.w - m) * LOG2E);

    float sum = ((a.x + a.y) + (a.z + a.w)) + ((b.x + b.y) + (b.z + b.w));
#pragma unroll
    for (int off = 32; off; off >>= 1) sum += __shfl_xor(sum, off);

    const float inv = fast_rcp(sum);
    a.x *= inv; a.y *= inv; a.z *= inv; a.w *= inv;
    b.x *= inv; b.y *= inv; b.z *= inv; b.w *= inv;
    po[t] = a; po[t + 64] = b;
}

// ---------------------------------------------------------------------------
// K4: out = attn @ value. Block: 32(q) x 64(i) tile, k chunked by 64.
// 256 threads, each 2(q) x 4(i). Grid (4,16,4) = 256 blocks.
// ---------------------------------------------------------------------------
#define AT_ST 68
#define VT_ST 68
__global__ __launch_bounds__(256) void pv_kernel(
    const float* __restrict__ attn, const float* __restrict__ value,
    float* __restrict__ out)
{
    __shared__ float a_lds[32 * AT_ST];
    __shared__ float v_lds[64 * VT_ST];

    const int t = threadIdx.x;
    const int tx = t & 15, ty = t >> 4;
    const int b = blockIdx.z, qt = blockIdx.y, it = blockIdx.x;
    const int q0 = qt * 32, i0 = it * 64;
    const float* abase = attn + (size_t)(b * 512 + q0) * 512;
    const float* vbase = value + (size_t)(b * 512) * 256 + i0;

    float4 acc0 = {0, 0, 0, 0}, acc1 = {0, 0, 0, 0};

    for (int kc = 0; kc < 512; kc += 64) {
        __syncthreads();
#pragma unroll
        for (int l = 0; l < 2; ++l) {
            const int f = t + 256 * l;
            const int row = f >> 4, c4 = (f & 15) * 4;
            *(float4*)&a_lds[row * AT_ST + c4] = *(const float4*)&abase[row * 512 + kc + c4];
        }
#pragma unroll
        for (int l = 0; l < 4; ++l) {
            const int f = t + 256 * l;
            const int row = f >> 4, c4 = (f & 15) * 4;
            *(float4*)&v_lds[row * VT_ST + c4] = *(const float4*)&vbase[(size_t)(kc + row) * 256 + c4];
        }
        __syncthreads();

        for (int k = 0; k < 64; ++k) {
            const float a0 = a_lds[(ty * 2 + 0) * AT_ST + k];
            const float a1 = a_lds[(ty * 2 + 1) * AT_ST + k];
            const float4 v = *(const float4*)&v_lds[k * VT_ST + tx * 4];
            acc0.x = fmaf(a0, v.x, acc0.x); acc0.y = fmaf(a0, v.y, acc0.y);
            acc0.z = fmaf(a0, v.z, acc0.z); acc0.w = fmaf(a0, v.w, acc0.w);
            acc1.x = fmaf(a1, v.x, acc1.x); acc1.y = fmaf(a1, v.y, acc1.y);
            acc1.z = fmaf(a1, v.z, acc1.z); acc1.w = fmaf(a1, v.w, acc1.w);
        }
    }

    float* obase = out + (size_t)(b * 512 + q0) * 256 + i0;
    *(float4*)&obase[(ty * 2 + 0) * 256 + tx * 4] = acc0;
    *(float4*)&obase[(ty * 2 + 1) * 256 + tx * 4] = acc1;
}

extern "C" void kernel_launch(void* const* d_in, const int* in_sizes, int n_in,
                              void* d_out, int out_size, void* d_ws, size_t ws_size,
                              hipStream_t stream) {
    const float* query = (const float*)d_in[0];
    const float* value = (const float*)d_in[1];
    const float* Wq    = (const float*)d_in[2];
    const float* Wv    = (const float*)d_in[3];
    const float* scale = (const float*)d_in[4];

    float* out0 = (float*)d_out;                 // [4,512,256]
    float* attn = out0 + 4 * 512 * 256;          // [4,512,512]

    float* eq    = (float*)d_ws;                 // [2048,256]
    float* ek    = eq + 2048 * 256;              // [2048,256]
    float* part0 = ek + 2048 * 256;              // [4,512,512] d-half 0
    float* part1 = part0 + 4 * 512 * 512;        // [4,512,512] d-half 1

    proj_kernel<<<512, 256, 0, stream>>>(query, value, Wq, Wv, eq, ek);
    scores_kernel<<<dim3(16, 16, 8), 256, 0, stream>>>(eq, ek, scale, part0, part1);
    softmax_kernel<<<2048, 64, 0, stream>>>(part0, part1, attn);
    pv_kernel<<<dim3(4, 16, 4), 256, 0, stream>>>(attn, value, out0);
}